// Round 10
// baseline (121.230 us; speedup 1.0000x reference)
//
#include <hip/hip_runtime.h>

// Sinkhorn fixed-point for fermionic canonical ensembles.
// B=2048 systems, P=64 orbitals, N_PART=32, n_iters from d_in[2].
//
// R9 = R8 (passed, absmax 0.015625, 68.3us rocprof) + ONE value-preserving
// change: the 32 C-block eps-gathers (__shfl -> ds_bpermute) are preloaded
// and PINNED before the exp block, exactly like R8 did for the 31 Er
// gathers. R8 post-mortem: per-wave stall ~5700 cyc/iter >> sweep chain
// ~1550; the gap is ~32 serialized bpermute->waitcnt->use sequences in the
// C-block (~55 cyc each). Batching them drains the DS pipe with ~one wait.
// Bit-identical values: same shuffles/inputs, accumulation order untouched
// (expect absmax == 0.015625 exactly; any drift falsifies this).
// Everything else unchanged from R8: contract(off), Cody-Waite exp/log,
// numpy pairwise-sum order, ~1ulp rcp_nr, amdgpu_waves_per_eu(2,2),
// register shuffles only, no LDS, no barriers.

#pragma clang fp contract(off)

#define NPART 32
#define PORB  64

#define L2E_HI 1.44269502162933349609375f
#define L2E_LO 1.9259629911266175e-08f
#define LN2_HI 0.69314718246459960938f
#define LN2_LO -1.9046542121259175e-09f
#define LN2F   0.6931471805599453f

__device__ __forceinline__ float readlane_f(float v, int srclane) {
    return __int_as_float(__builtin_amdgcn_readlane(__float_as_int(v), srclane));
}

// reciprocal: v_rcp_f32 + one Newton step => ~0.5-1 ulp
__device__ __forceinline__ float rcp_nr(float d) {
    float r = __builtin_amdgcn_rcpf(d);
    float e = fmaf(-d, r, 1.0f);
    return fmaf(r, e, r);
}

// e^arg with Cody-Waite correction (<=1.5 ulp), arg pre-rounded like numpy
__device__ __forceinline__ float exp_acc(float arg) {
    float p    = arg * L2E_HI;
    float perr = fmaf(arg, L2E_HI, -p);
    float c    = fmaf(arg, L2E_LO, perr);
    float e0   = __builtin_amdgcn_exp2f(p);
    return fmaf(e0, c * LN2F, e0);
}

// ln(x) = log2(x)*ln2 with split constant (~1.5 ulp)
__device__ __forceinline__ float ln_acc(float x) {
    float l2 = __log2f(x);
    float p  = l2 * LN2_HI;
    float e  = fmaf(l2, LN2_HI, -p);
    return p + fmaf(l2, LN2_LO, e);
}

// numpy pairwise_sum order for 64 elements (identical to R4/R5/R7/R8)
__device__ __forceinline__ float pairwise_np(float v, int lane) {
    float c = v;
    #pragma unroll
    for (int i = 1; i < 8; ++i)
        c = c + __shfl(v, (lane + 8 * i) & 63);
    float r0 = readlane_f(c, 0), r1 = readlane_f(c, 1);
    float r2 = readlane_f(c, 2), r3 = readlane_f(c, 3);
    float r4 = readlane_f(c, 4), r5 = readlane_f(c, 5);
    float r6 = readlane_f(c, 6), r7 = readlane_f(c, 7);
    return ((r0 + r1) + (r2 + r3)) + ((r4 + r5) + (r6 + r7));
}

__global__ __launch_bounds__(PORB)
__attribute__((amdgpu_waves_per_eu(2, 2)))
void sinkhorn_kernel(
    const float* __restrict__ n_in,
    const float* __restrict__ beta_ptr,
    const int*   __restrict__ iters_ptr,
    float*       __restrict__ out)
{
    const int b    = blockIdx.x;
    const int lane = threadIdx.x;               // orbital index p
    const float beta    = beta_ptr[0];
    const int   n_iters = iters_ptr[0];
    const float nb      = -beta;
    const float inv_beta = rcp_nr(beta);

    const float n_p = n_in[b * PORB + lane];

    // ---- setup: nn, snn, ratio, eps0 (identical to R5/R7/R8) ----
    const float srt = pairwise_np(n_p, lane);
    const float nn  = (n_p * rcp_nr(srt)) * (float)NPART;
    const float snn = pairwise_np(nn, lane);
    const float inv_snn  = rcp_nr(snn);
    const float ratio_nn = nn * rcp_nr(1.0f - nn);
    float eps = (-ln_acc(ratio_nn)) * inv_beta; // eps_GC_guess

    // per-lane constants for the C_k block
    const float kf    = (float)((lane & 31) + 1);
    const float mk    = nb * kf;
    const int   jbase = (lane & 32) >> 3;
    (void)kf;

    for (int it = 0; it < n_iters; ++it) {
        // ---- preload + pin the 32 eps-gathers (value-identical to R8's
        // inline shuffles; batches the ds_bpermutes so the DS latency is
        // paid once, not ~32 times serially) ----
        float ejv[4][8];
        #pragma unroll
        for (int jj = 0; jj < 4; ++jj) {
            #pragma unroll
            for (int i = 0; i < 8; ++i) {
                const int idx = jbase + jj + 8 * i;
                ejv[jj][i] = __shfl(eps, idx);
                asm volatile("" : "+v"(ejv[jj][i]));     // schedule pin only
            }
        }

        // ---- C_k = sum_p exp(-beta*k*eps_p), numpy pairwise order ----
        float acc[4];
        #pragma unroll
        for (int jj = 0; jj < 4; ++jj) {
            #pragma unroll
            for (int i = 0; i < 8; ++i) {
                const float arg = mk * ejv[jj][i];
                const float v   = exp_acc(arg);
                acc[jj] = (i == 0) ? v : (acc[jj] + v);
            }
        }
        float shalf = (acc[0] + acc[1]) + (acc[2] + acc[3]);
        float Cfull = shalf + __shfl_xor(shalf, 32);
        // lane i in 0..31 holds C[i+1]

        const float c1 = readlane_f(Cfull, 0);           // C[1]

        // E_np[i] = C[i+1]/C[i] (lane0 junk, never read)
        const float prevC = __shfl(Cfull, (lane - 1) & 63);
        const float E     = Cfull * rcp_nr(prevC);

        // ---- preload + pin the 31 E-gathers (as in R8) ----
        float Er[NPART];
        #pragma unroll
        for (int s = 1; s < NPART; ++s) {
            Er[s] = __shfl(E, (lane + 1 - s) & 63);
            asm volatile("" : "+v"(Er[s]));              // schedule pin only
        }

        // ---- lane-pipelined Q recursion: lane l carries M=l+1 ----
        // invQ[s] = (s+1) * rcp_nr(c1 * ps)   (exact R5 formula/rounding)
        float invQ[NPART];
        invQ[0] = rcp_nr(c1);
        float p = 1.0f;
        #pragma unroll
        for (int s = 1; s < NPART; ++s) {
            const float d  = Er[s] * invQ[s - 1];
            const float m  = d * p;
            p = 1.0f - m;
            const float ps = readlane_f(p, s);
            invQ[s] = (float)(s + 1) * rcp_nr(c1 * ps);
        }

        // ---- aux: 32-step recursion; x*invQ[k] all off-chain ----
        const float x = exp_acc(nb * eps);
        float g[NPART];
        #pragma unroll
        for (int k = 0; k < NPART; ++k) g[k] = x * invQ[k];  // parallel
        float prev = 1.0f, y30 = 0.0f;
        #pragma unroll
        for (int k = 0; k < NPART; ++k) {
            const float m = g[k] * prev;
            prev = 1.0f - m;                                 // chain: mul+sub
            if (k == NPART - 2) y30 = prev;
        }
        const float Qp1 = prev;                              // ys[N-1]
        const float Qp0 = y30 * invQ[NPART - 1];             // ys[N-2]/Q[N-1]

        // ---- update + normalize (identical to R5/R7/R8) ----
        const float q_arg   = (ratio_nn * Qp1) * rcp_nr(Qp0);
        const float eps_new = (-ln_acc(q_arg)) * inv_beta;

        const float W = pairwise_np(nn * eps_new, lane);
        eps = eps_new - (W * inv_snn);
    }

    out[b * PORB + lane] = eps;
}

extern "C" void kernel_launch(void* const* d_in, const int* in_sizes, int n_in,
                              void* d_out, int out_size, void* d_ws, size_t ws_size,
                              hipStream_t stream) {
    const float* n_ptr    = (const float*)d_in[0];
    const float* beta_ptr = (const float*)d_in[1];
    const int*   it_ptr   = (const int*)d_in[2];
    float*       out      = (float*)d_out;

    const int B = in_sizes[0] / PORB;   // 2048 systems
    sinkhorn_kernel<<<B, PORB, 0, stream>>>(n_ptr, beta_ptr, it_ptr, out);
}

// Round 11
// 115.322 us; speedup vs baseline: 1.0512x; 1.0512x over previous
//
#include <hip/hip_runtime.h>

// Sinkhorn fixed-point for fermionic canonical ensembles.
// B=2048 systems, P=64 orbitals, N_PART=32, n_iters from d_in[2].
//
// R10 = R8 (best: 68.3us rocprof, absmax 0.015625) + ONE value-identical
// mechanical change, after R9's regression taught us the ejv pin batching
// was counterproductive (pins add copies; (shfl;pin) pairs sink anyway):
//  * C-block gathers: for fixed i, the four jj operands eps[jbase+jj+8i]
//    are 4 CONSECUTIVE floats. Stage eps in LDS (1 ds_write + barriers,
//    R0-proven pattern) and read 8x ds_read_b128 per lane instead of 32x
//    ds_bpermute. Addresses are uniform per half-wave => broadcast,
//    conflict-free, 16B-aligned. Same values, same accumulation order
//    (sequential in i per acc[jj]) => bit-identical trajectory.
//  * ejv pins from R9 dropped (regression); Er preload + pins kept (R8 win).
// Accuracy posture unchanged: contract(off), Cody-Waite exp/log, numpy
// pairwise-sum order, ~1ulp rcp_nr, amdgpu_waves_per_eu(2,2).

#pragma clang fp contract(off)

#define NPART 32
#define PORB  64

#define L2E_HI 1.44269502162933349609375f
#define L2E_LO 1.9259629911266175e-08f
#define LN2_HI 0.69314718246459960938f
#define LN2_LO -1.9046542121259175e-09f
#define LN2F   0.6931471805599453f

__device__ __forceinline__ float readlane_f(float v, int srclane) {
    return __int_as_float(__builtin_amdgcn_readlane(__float_as_int(v), srclane));
}

// reciprocal: v_rcp_f32 + one Newton step => ~0.5-1 ulp
__device__ __forceinline__ float rcp_nr(float d) {
    float r = __builtin_amdgcn_rcpf(d);
    float e = fmaf(-d, r, 1.0f);
    return fmaf(r, e, r);
}

// e^arg with Cody-Waite correction (<=1.5 ulp), arg pre-rounded like numpy
__device__ __forceinline__ float exp_acc(float arg) {
    float p    = arg * L2E_HI;
    float perr = fmaf(arg, L2E_HI, -p);
    float c    = fmaf(arg, L2E_LO, perr);
    float e0   = __builtin_amdgcn_exp2f(p);
    return fmaf(e0, c * LN2F, e0);
}

// ln(x) = log2(x)*ln2 with split constant (~1.5 ulp)
__device__ __forceinline__ float ln_acc(float x) {
    float l2 = __log2f(x);
    float p  = l2 * LN2_HI;
    float e  = fmaf(l2, LN2_HI, -p);
    return p + fmaf(l2, LN2_LO, e);
}

// numpy pairwise_sum order for 64 elements (identical to R4..R9)
__device__ __forceinline__ float pairwise_np(float v, int lane) {
    float c = v;
    #pragma unroll
    for (int i = 1; i < 8; ++i)
        c = c + __shfl(v, (lane + 8 * i) & 63);
    float r0 = readlane_f(c, 0), r1 = readlane_f(c, 1);
    float r2 = readlane_f(c, 2), r3 = readlane_f(c, 3);
    float r4 = readlane_f(c, 4), r5 = readlane_f(c, 5);
    float r6 = readlane_f(c, 6), r7 = readlane_f(c, 7);
    return ((r0 + r1) + (r2 + r3)) + ((r4 + r5) + (r6 + r7));
}

__global__ __launch_bounds__(PORB)
__attribute__((amdgpu_waves_per_eu(2, 2)))
void sinkhorn_kernel(
    const float* __restrict__ n_in,
    const float* __restrict__ beta_ptr,
    const int*   __restrict__ iters_ptr,
    float*       __restrict__ out)
{
    const int b    = blockIdx.x;
    const int lane = threadIdx.x;               // orbital index p
    const float beta    = beta_ptr[0];
    const int   n_iters = iters_ptr[0];
    const float nb      = -beta;
    const float inv_beta = rcp_nr(beta);

    __shared__ float t_sh[PORB];                // eps staging for the C-block

    const float n_p = n_in[b * PORB + lane];

    // ---- setup: nn, snn, ratio, eps0 (identical to R5/R7/R8) ----
    const float srt = pairwise_np(n_p, lane);
    const float nn  = (n_p * rcp_nr(srt)) * (float)NPART;
    const float snn = pairwise_np(nn, lane);
    const float inv_snn  = rcp_nr(snn);
    const float ratio_nn = nn * rcp_nr(1.0f - nn);
    float eps = (-ln_acc(ratio_nn)) * inv_beta; // eps_GC_guess

    // per-lane constants for the C_k block
    const float kf    = (float)((lane & 31) + 1);
    const float mk    = nb * kf;
    const int   jbase = (lane & 32) >> 3;       // 0 (half0) or 4 (half1)
    const int   q4    = jbase >> 2;             // float4-index offset: 0 or 1
    (void)kf;

    for (int it = 0; it < n_iters; ++it) {
        // ---- stage eps in LDS (barrier-bracketed; R0-proven pattern) ----
        __syncthreads();                        // WAR vs prev iter's reads
        t_sh[lane] = eps;
        __syncthreads();                        // RAW for this iter's reads

        // ---- C_k = sum_p exp(-beta*k*eps_p), numpy pairwise order.
        // For fixed i the four jj operands are consecutive floats:
        // one ds_read_b128 per i (uniform addr per half => broadcast).
        const float4* t4 = reinterpret_cast<const float4*>(t_sh);
        float4 v4[8];
        #pragma unroll
        for (int i = 0; i < 8; ++i)
            v4[i] = t4[2 * i + q4];             // eps[jbase+8i .. jbase+8i+3]

        float acc[4];
        #pragma unroll
        for (int i = 0; i < 8; ++i) {
            const float e0 = exp_acc(mk * v4[i].x);
            const float e1 = exp_acc(mk * v4[i].y);
            const float e2 = exp_acc(mk * v4[i].z);
            const float e3 = exp_acc(mk * v4[i].w);
            if (i == 0) { acc[0] = e0; acc[1] = e1; acc[2] = e2; acc[3] = e3; }
            else        { acc[0] += e0; acc[1] += e1; acc[2] += e2; acc[3] += e3; }
        }
        float shalf = (acc[0] + acc[1]) + (acc[2] + acc[3]);
        float Cfull = shalf + __shfl_xor(shalf, 32);
        // lane i in 0..31 holds C[i+1]

        const float c1 = readlane_f(Cfull, 0);           // C[1]

        // E_np[i] = C[i+1]/C[i] (lane0 junk, never read)
        const float prevC = __shfl(Cfull, (lane - 1) & 63);
        const float E     = Cfull * rcp_nr(prevC);

        // ---- preload + pin the 31 E-gathers (exactly as R8) ----
        float Er[NPART];
        #pragma unroll
        for (int s = 1; s < NPART; ++s) {
            Er[s] = __shfl(E, (lane + 1 - s) & 63);
            asm volatile("" : "+v"(Er[s]));              // schedule pin only
        }

        // ---- lane-pipelined Q recursion: lane l carries M=l+1 ----
        // invQ[s] = (s+1) * rcp_nr(c1 * ps)   (exact R5 formula/rounding)
        float invQ[NPART];
        invQ[0] = rcp_nr(c1);
        float p = 1.0f;
        #pragma unroll
        for (int s = 1; s < NPART; ++s) {
            const float d  = Er[s] * invQ[s - 1];
            const float m  = d * p;
            p = 1.0f - m;
            const float ps = readlane_f(p, s);
            invQ[s] = (float)(s + 1) * rcp_nr(c1 * ps);
        }

        // ---- aux: 32-step recursion; x*invQ[k] all off-chain ----
        const float x = exp_acc(nb * eps);
        float g[NPART];
        #pragma unroll
        for (int k = 0; k < NPART; ++k) g[k] = x * invQ[k];  // parallel
        float prev = 1.0f, y30 = 0.0f;
        #pragma unroll
        for (int k = 0; k < NPART; ++k) {
            const float m = g[k] * prev;
            prev = 1.0f - m;                                 // chain: mul+sub
            if (k == NPART - 2) y30 = prev;
        }
        const float Qp1 = prev;                              // ys[N-1]
        const float Qp0 = y30 * invQ[NPART - 1];             // ys[N-2]/Q[N-1]

        // ---- update + normalize (identical to R5/R7/R8) ----
        const float q_arg   = (ratio_nn * Qp1) * rcp_nr(Qp0);
        const float eps_new = (-ln_acc(q_arg)) * inv_beta;

        const float W = pairwise_np(nn * eps_new, lane);
        eps = eps_new - (W * inv_snn);
    }

    out[b * PORB + lane] = eps;
}

extern "C" void kernel_launch(void* const* d_in, const int* in_sizes, int n_in,
                              void* d_out, int out_size, void* d_ws, size_t ws_size,
                              hipStream_t stream) {
    const float* n_ptr    = (const float*)d_in[0];
    const float* beta_ptr = (const float*)d_in[1];
    const int*   it_ptr   = (const int*)d_in[2];
    float*       out      = (float*)d_out;

    const int B = in_sizes[0] / PORB;   // 2048 systems
    sinkhorn_kernel<<<B, PORB, 0, stream>>>(n_ptr, beta_ptr, it_ptr, out);
}

// Round 12
// 109.926 us; speedup vs baseline: 1.1028x; 1.0491x over previous
//
#include <hip/hip_runtime.h>

// Sinkhorn fixed-point for fermionic canonical ensembles.
// B=2048 systems, P=64 orbitals, N_PART=32, n_iters from d_in[2].
//
// R11: PACK 2 SYSTEMS PER WAVE (system A = lanes 0-31, B = lanes 32-63).
// R10 post-mortem: 2 lockstep waves/SIMD expose ~36% idle issue (VALUBusy
// 64%) because both stall on the same ~1500-cyc sweep chain. Packing lets
// one wave's sweep traversal serve two systems (chain amortized 2x) and
// the aux/epilogue run 2 orbitals/lane (free ILP). Grid: 1024 blocks ->
// 1 wave/SIMD, waves_per_eu(1,1) (VGPR budget 512).
// EVERY per-system fp op, operand, and order is preserved exactly vs R10
// (absmax must be EXACTLY 0.015625 -- the correctness canary):
//  * C_k: lane k-1 of each half builds all 8 numpy accumulators
//    sequentially (same values/order; same final tree grouping).
//  * sweep: per-half ps/c1 via uniform readlanes + select (no fp change).
//  * reductions: numpy 8-term order from (v0,v1) pair + 16 readlanes +
//    identical tree; per-half select.
// Accuracy posture unchanged: contract(off), Cody-Waite exp/log, ~1ulp
// rcp_nr, Er preload+pins (R8 win), LDS staging barrier-bracketed.

#pragma clang fp contract(off)

#define NPART 32
#define PORB  64

#define L2E_HI 1.44269502162933349609375f
#define L2E_LO 1.9259629911266175e-08f
#define LN2_HI 0.69314718246459960938f
#define LN2_LO -1.9046542121259175e-09f
#define LN2F   0.6931471805599453f

__device__ __forceinline__ float readlane_f(float v, int srclane) {
    return __int_as_float(__builtin_amdgcn_readlane(__float_as_int(v), srclane));
}

// reciprocal: v_rcp_f32 + one Newton step => ~0.5-1 ulp
__device__ __forceinline__ float rcp_nr(float d) {
    float r = __builtin_amdgcn_rcpf(d);
    float e = fmaf(-d, r, 1.0f);
    return fmaf(r, e, r);
}

// e^arg with Cody-Waite correction (<=1.5 ulp), arg pre-rounded like numpy
__device__ __forceinline__ float exp_acc(float arg) {
    float p    = arg * L2E_HI;
    float perr = fmaf(arg, L2E_HI, -p);
    float c    = fmaf(arg, L2E_LO, perr);
    float e0   = __builtin_amdgcn_exp2f(p);
    return fmaf(e0, c * LN2F, e0);
}

// ln(x) = log2(x)*ln2 with split constant (~1.5 ulp)
__device__ __forceinline__ float ln_acc(float x) {
    float l2 = __log2f(x);
    float p  = l2 * LN2_HI;
    float e  = fmaf(l2, LN2_HI, -p);
    return p + fmaf(l2, LN2_LO, e);
}

// shuffle within the lane's own 32-lane half
__device__ __forceinline__ float shfl32(float v, int idx, int hbit) {
    return __shfl(v, (idx & 31) | hbit);
}

// numpy pairwise_sum over one system's 64 orbitals, values held as
// (v0,v1) on 32 lanes per half. Term order on lane j (j=0..7):
//   r[j] = v0[j]+v0[j+8]+v0[j+16]+v0[j+24]+v1[j]+v1[j+8]+v1[j+16]+v1[j+24]
// == numpy's v[j]+v[j+8]+...+v[j+56] (orbital p<32 -> v0[p], p>=32 -> v1[p-32]).
// Final tree ((r0+r1)+(r2+r3))+((r4+r5)+(r6+r7)) identical to R4..R10.
__device__ __forceinline__ float red_np(float v0, float v1, int l32, int hbit) {
    float c = v0;
    c = c + shfl32(v0, l32 + 8,  hbit);
    c = c + shfl32(v0, l32 + 16, hbit);
    c = c + shfl32(v0, l32 + 24, hbit);
    c = c + v1;
    c = c + shfl32(v1, l32 + 8,  hbit);
    c = c + shfl32(v1, l32 + 16, hbit);
    c = c + shfl32(v1, l32 + 24, hbit);
    // lanes hbit+j (j=0..7) hold r[j] of their system
    const float ta = ((readlane_f(c, 0) + readlane_f(c, 1)) +
                      (readlane_f(c, 2) + readlane_f(c, 3))) +
                     ((readlane_f(c, 4) + readlane_f(c, 5)) +
                      (readlane_f(c, 6) + readlane_f(c, 7)));
    const float tb = ((readlane_f(c, 32) + readlane_f(c, 33)) +
                      (readlane_f(c, 34) + readlane_f(c, 35))) +
                     ((readlane_f(c, 36) + readlane_f(c, 37)) +
                      (readlane_f(c, 38) + readlane_f(c, 39)));
    return hbit ? tb : ta;
}

__global__ __launch_bounds__(PORB)
__attribute__((amdgpu_waves_per_eu(1, 1)))
void sinkhorn_kernel(
    const float* __restrict__ n_in,
    const float* __restrict__ beta_ptr,
    const int*   __restrict__ iters_ptr,
    float*       __restrict__ out)
{
    const int b    = blockIdx.x;                // pair index
    const int lane = threadIdx.x;
    const int l32  = lane & 31;
    const int hbit = lane & 32;                 // 0 (system A) / 32 (system B)
    const int h    = hbit >> 5;

    const float beta    = beta_ptr[0];
    const int   n_iters = iters_ptr[0];
    const float nb      = -beta;
    const float inv_beta = rcp_nr(beta);

    __shared__ __align__(16) float t_sh[2 * PORB];  // eps staging, 2 systems

    const int sysbase = (2 * b + h) * PORB;
    const float n0 = n_in[sysbase + l32];           // orbital l32
    const float n1 = n_in[sysbase + 32 + l32];      // orbital l32+32

    // ---- setup: nn, snn, ratio, eps0 (per-system values == R10) ----
    const float srt  = red_np(n0, n1, l32, hbit);
    const float isrt = rcp_nr(srt);
    const float nn0  = (n0 * isrt) * (float)NPART;
    const float nn1  = (n1 * isrt) * (float)NPART;
    const float snn  = red_np(nn0, nn1, l32, hbit);
    const float inv_snn = rcp_nr(snn);
    const float ratio0  = nn0 * rcp_nr(1.0f - nn0);
    const float ratio1  = nn1 * rcp_nr(1.0f - nn1);
    float eps0 = (-ln_acc(ratio0)) * inv_beta;
    float eps1 = (-ln_acc(ratio1)) * inv_beta;

    const float kf = (float)(l32 + 1);              // this lane's k
    const float mk = nb * kf;

    for (int it = 0; it < n_iters; ++it) {
        // ---- stage both systems' eps (barrier-bracketed fences) ----
        __syncthreads();
        t_sh[2 * hbit + l32]      = eps0;           // 2*hbit == h*64
        t_sh[2 * hbit + 32 + l32] = eps1;
        __syncthreads();

        // ---- C_k: this lane computes its system's C_{l32+1} alone.
        // acc[jj] = numpy r[jj] (8 terms, sequential in i); reads are
        // 2x ds_read_b128 per i (uniform addr per half => broadcast).
        const float4* t4 = reinterpret_cast<const float4*>(t_sh);
        float acc[8];
        #pragma unroll
        for (int i = 0; i < 8; ++i) {
            const float4 va = t4[(h << 4) + 2 * i];      // eps[8i .. 8i+3]
            const float4 vb = t4[(h << 4) + 2 * i + 1];  // eps[8i+4 .. 8i+7]
            const float e0 = exp_acc(mk * va.x);
            const float e1 = exp_acc(mk * va.y);
            const float e2 = exp_acc(mk * va.z);
            const float e3 = exp_acc(mk * va.w);
            const float e4 = exp_acc(mk * vb.x);
            const float e5 = exp_acc(mk * vb.y);
            const float e6 = exp_acc(mk * vb.z);
            const float e7 = exp_acc(mk * vb.w);
            if (i == 0) {
                acc[0] = e0; acc[1] = e1; acc[2] = e2; acc[3] = e3;
                acc[4] = e4; acc[5] = e5; acc[6] = e6; acc[7] = e7;
            } else {
                acc[0] += e0; acc[1] += e1; acc[2] += e2; acc[3] += e3;
                acc[4] += e4; acc[5] += e5; acc[6] += e6; acc[7] += e7;
            }
        }
        const float Cfull = ((acc[0] + acc[1]) + (acc[2] + acc[3])) +
                            ((acc[4] + acc[5]) + (acc[6] + acc[7]));
        // lane hbit + (k-1) holds C[k] of its system

        const float c1A = readlane_f(Cfull, 0);
        const float c1B = readlane_f(Cfull, 32);
        const float c1v = hbit ? c1B : c1A;          // per-half C[1]

        // E[i] = C[i+1]/C[i] (l32==0 junk, never consumed by live lanes)
        const float prevC = __shfl(Cfull, ((l32 - 1) & 31) | hbit);
        const float E     = Cfull * rcp_nr(prevC);

        // ---- preload + pin the 31 E-gathers (R8 win) ----
        float Er[NPART];
        #pragma unroll
        for (int s = 1; s < NPART; ++s) {
            Er[s] = __shfl(E, ((l32 + 1 - s) & 31) | hbit);
            asm volatile("" : "+v"(Er[s]));          // schedule pin only
        }

        // ---- lane-pipelined Q sweep, both systems per traversal ----
        // invQ[s] = (s+1) * rcp_nr(c1 * ps)   (exact R5/R10 rounding)
        float invQ[NPART];
        invQ[0] = rcp_nr(c1v);
        float p = 1.0f;
        #pragma unroll
        for (int s = 1; s < NPART; ++s) {
            const float d = Er[s] * invQ[s - 1];
            const float m = d * p;
            p = 1.0f - m;
            const float psA = readlane_f(p, s);
            const float psB = readlane_f(p, 32 + s);
            const float psv = hbit ? psB : psA;
            invQ[s] = (float)(s + 1) * rcp_nr(c1v * psv);
        }

        // ---- aux: 2 orbitals/lane, two interleaved mul+sub chains ----
        const float x0 = exp_acc(nb * eps0);
        const float x1 = exp_acc(nb * eps1);
        float g0[NPART], g1[NPART];
        #pragma unroll
        for (int k = 0; k < NPART; ++k) { g0[k] = x0 * invQ[k];
                                          g1[k] = x1 * invQ[k]; }
        float prev0 = 1.0f, prev1 = 1.0f, y30_0 = 0.0f, y30_1 = 0.0f;
        #pragma unroll
        for (int k = 0; k < NPART; ++k) {
            const float m0 = g0[k] * prev0;
            const float m1 = g1[k] * prev1;
            prev0 = 1.0f - m0;
            prev1 = 1.0f - m1;
            if (k == NPART - 2) { y30_0 = prev0; y30_1 = prev1; }
        }
        const float Qp1_0 = prev0,                Qp1_1 = prev1;
        const float Qp0_0 = y30_0 * invQ[NPART - 1];
        const float Qp0_1 = y30_1 * invQ[NPART - 1];

        // ---- update + normalize (per-orbital, values == R10) ----
        const float q0 = (ratio0 * Qp1_0) * rcp_nr(Qp0_0);
        const float q1 = (ratio1 * Qp1_1) * rcp_nr(Qp0_1);
        const float en0 = (-ln_acc(q0)) * inv_beta;
        const float en1 = (-ln_acc(q1)) * inv_beta;

        const float W = red_np(nn0 * en0, nn1 * en1, l32, hbit);
        const float corr = W * inv_snn;
        eps0 = en0 - corr;
        eps1 = en1 - corr;
    }

    out[sysbase + l32]      = eps0;
    out[sysbase + 32 + l32] = eps1;
}

extern "C" void kernel_launch(void* const* d_in, const int* in_sizes, int n_in,
                              void* d_out, int out_size, void* d_ws, size_t ws_size,
                              hipStream_t stream) {
    const float* n_ptr    = (const float*)d_in[0];
    const float* beta_ptr = (const float*)d_in[1];
    const int*   it_ptr   = (const int*)d_in[2];
    float*       out      = (float*)d_out;

    const int B = in_sizes[0] / PORB;   // 2048 systems
    sinkhorn_kernel<<<B / 2, PORB, 0, stream>>>(n_ptr, beta_ptr, it_ptr, out);
}

// Round 13
// 109.851 us; speedup vs baseline: 1.1036x; 1.0007x over previous
//
#include <hip/hip_runtime.h>

// Sinkhorn fixed-point for fermionic canonical ensembles.
// B=2048 systems, P=64 orbitals, N_PART=32, n_iters from d_in[2].
//
// R12 = R11 (passed, absmax 0.015625, 60.7us rocprof) + aux-into-sweep
// fusion, value-identical. R11 post-mortem: 1 wave/SIMD, VALUBusy 57% ->
// ~3100 cyc/iter of single-wave stalls, concentrated in the 31-step sweep
// (~35-cyc carried chain, only ~24 cyc of issue per step). The aux
// recursion consumes invQ[k] in exactly the production order, so each aux
// step (2 muls + sub per system, same ops/order/rounding as R11's separate
// loop) executes right after its invQ[s] is formed, filling the sweep's
// dead cycles. x0/x1 hoisted (depend only on eps). g[] arrays and invQ[]
// array eliminated (scalar carry + invQ31) -> ~60 fewer VGPRs.
// Everything else identical to R11: pack-2 systems/wave, per-system numpy
// op order, contract(off), Cody-Waite exp/log, ~1ulp rcp_nr, Er preload +
// volatile pins, waves_per_eu(1,1), barrier-bracketed LDS staging.
// CANARY: absmax must be exactly 0.015625.

#pragma clang fp contract(off)

#define NPART 32
#define PORB  64

#define L2E_HI 1.44269502162933349609375f
#define L2E_LO 1.9259629911266175e-08f
#define LN2_HI 0.69314718246459960938f
#define LN2_LO -1.9046542121259175e-09f
#define LN2F   0.6931471805599453f

__device__ __forceinline__ float readlane_f(float v, int srclane) {
    return __int_as_float(__builtin_amdgcn_readlane(__float_as_int(v), srclane));
}

// reciprocal: v_rcp_f32 + one Newton step => ~0.5-1 ulp
__device__ __forceinline__ float rcp_nr(float d) {
    float r = __builtin_amdgcn_rcpf(d);
    float e = fmaf(-d, r, 1.0f);
    return fmaf(r, e, r);
}

// e^arg with Cody-Waite correction (<=1.5 ulp), arg pre-rounded like numpy
__device__ __forceinline__ float exp_acc(float arg) {
    float p    = arg * L2E_HI;
    float perr = fmaf(arg, L2E_HI, -p);
    float c    = fmaf(arg, L2E_LO, perr);
    float e0   = __builtin_amdgcn_exp2f(p);
    return fmaf(e0, c * LN2F, e0);
}

// ln(x) = log2(x)*ln2 with split constant (~1.5 ulp)
__device__ __forceinline__ float ln_acc(float x) {
    float l2 = __log2f(x);
    float p  = l2 * LN2_HI;
    float e  = fmaf(l2, LN2_HI, -p);
    return p + fmaf(l2, LN2_LO, e);
}

// shuffle within the lane's own 32-lane half
__device__ __forceinline__ float shfl32(float v, int idx, int hbit) {
    return __shfl(v, (idx & 31) | hbit);
}

// numpy pairwise_sum over one system's 64 orbitals (identical to R11)
__device__ __forceinline__ float red_np(float v0, float v1, int l32, int hbit) {
    float c = v0;
    c = c + shfl32(v0, l32 + 8,  hbit);
    c = c + shfl32(v0, l32 + 16, hbit);
    c = c + shfl32(v0, l32 + 24, hbit);
    c = c + v1;
    c = c + shfl32(v1, l32 + 8,  hbit);
    c = c + shfl32(v1, l32 + 16, hbit);
    c = c + shfl32(v1, l32 + 24, hbit);
    const float ta = ((readlane_f(c, 0) + readlane_f(c, 1)) +
                      (readlane_f(c, 2) + readlane_f(c, 3))) +
                     ((readlane_f(c, 4) + readlane_f(c, 5)) +
                      (readlane_f(c, 6) + readlane_f(c, 7)));
    const float tb = ((readlane_f(c, 32) + readlane_f(c, 33)) +
                      (readlane_f(c, 34) + readlane_f(c, 35))) +
                     ((readlane_f(c, 36) + readlane_f(c, 37)) +
                      (readlane_f(c, 38) + readlane_f(c, 39)));
    return hbit ? tb : ta;
}

__global__ __launch_bounds__(PORB)
__attribute__((amdgpu_waves_per_eu(1, 1)))
void sinkhorn_kernel(
    const float* __restrict__ n_in,
    const float* __restrict__ beta_ptr,
    const int*   __restrict__ iters_ptr,
    float*       __restrict__ out)
{
    const int b    = blockIdx.x;                // pair index
    const int lane = threadIdx.x;
    const int l32  = lane & 31;
    const int hbit = lane & 32;                 // 0 (system A) / 32 (system B)
    const int h    = hbit >> 5;

    const float beta    = beta_ptr[0];
    const int   n_iters = iters_ptr[0];
    const float nb      = -beta;
    const float inv_beta = rcp_nr(beta);

    __shared__ __align__(16) float t_sh[2 * PORB];  // eps staging, 2 systems

    const int sysbase = (2 * b + h) * PORB;
    const float n0 = n_in[sysbase + l32];           // orbital l32
    const float n1 = n_in[sysbase + 32 + l32];      // orbital l32+32

    // ---- setup: nn, snn, ratio, eps0 (per-system values == R11) ----
    const float srt  = red_np(n0, n1, l32, hbit);
    const float isrt = rcp_nr(srt);
    const float nn0  = (n0 * isrt) * (float)NPART;
    const float nn1  = (n1 * isrt) * (float)NPART;
    const float snn  = red_np(nn0, nn1, l32, hbit);
    const float inv_snn = rcp_nr(snn);
    const float ratio0  = nn0 * rcp_nr(1.0f - nn0);
    const float ratio1  = nn1 * rcp_nr(1.0f - nn1);
    float eps0 = (-ln_acc(ratio0)) * inv_beta;
    float eps1 = (-ln_acc(ratio1)) * inv_beta;

    const float kf = (float)(l32 + 1);              // this lane's k
    const float mk = nb * kf;

    for (int it = 0; it < n_iters; ++it) {
        // ---- stage both systems' eps (barrier-bracketed fences) ----
        __syncthreads();
        t_sh[2 * hbit + l32]      = eps0;           // 2*hbit == h*64
        t_sh[2 * hbit + 32 + l32] = eps1;
        __syncthreads();

        // ---- C_k: lane k-1 of each half builds all 8 numpy accumulators
        // (identical values/order to R11); 2x ds_read_b128 per i, uniform
        // address per half => broadcast, conflict-free.
        const float4* t4 = reinterpret_cast<const float4*>(t_sh);
        float acc[8];
        #pragma unroll
        for (int i = 0; i < 8; ++i) {
            const float4 va = t4[(h << 4) + 2 * i];      // eps[8i .. 8i+3]
            const float4 vb = t4[(h << 4) + 2 * i + 1];  // eps[8i+4 .. 8i+7]
            const float e0 = exp_acc(mk * va.x);
            const float e1 = exp_acc(mk * va.y);
            const float e2 = exp_acc(mk * va.z);
            const float e3 = exp_acc(mk * va.w);
            const float e4 = exp_acc(mk * vb.x);
            const float e5 = exp_acc(mk * vb.y);
            const float e6 = exp_acc(mk * vb.z);
            const float e7 = exp_acc(mk * vb.w);
            if (i == 0) {
                acc[0] = e0; acc[1] = e1; acc[2] = e2; acc[3] = e3;
                acc[4] = e4; acc[5] = e5; acc[6] = e6; acc[7] = e7;
            } else {
                acc[0] += e0; acc[1] += e1; acc[2] += e2; acc[3] += e3;
                acc[4] += e4; acc[5] += e5; acc[6] += e6; acc[7] += e7;
            }
        }
        const float Cfull = ((acc[0] + acc[1]) + (acc[2] + acc[3])) +
                            ((acc[4] + acc[5]) + (acc[6] + acc[7]));
        // lane hbit + (k-1) holds C[k] of its system

        const float c1A = readlane_f(Cfull, 0);
        const float c1B = readlane_f(Cfull, 32);
        const float c1v = hbit ? c1B : c1A;          // per-half C[1]

        // E[i] = C[i+1]/C[i] (l32==0 junk, never consumed by live lanes)
        const float prevC = __shfl(Cfull, ((l32 - 1) & 31) | hbit);
        const float E     = Cfull * rcp_nr(prevC);

        // ---- preload + pin the 31 E-gathers (R8 win) ----
        float Er[NPART];
        #pragma unroll
        for (int s = 1; s < NPART; ++s) {
            Er[s] = __shfl(E, ((l32 + 1 - s) & 31) | hbit);
            asm volatile("" : "+v"(Er[s]));          // schedule pin only
        }

        // ---- aux inputs, hoisted (depend only on eps) ----
        const float x0 = exp_acc(nb * eps0);
        const float x1 = exp_acc(nb * eps1);

        // ---- fused sweep + aux: lane-pipelined Q recursion with the aux
        // step s executed as soon as invQ[s] exists (same ops/order as
        // R11's separate loop -> bit-identical; fills sweep stall slots).
        const float invQ0 = rcp_nr(c1v);
        // aux step 0 (prev = 1.0 initially; g*1.0 is exact)
        float prev0, prev1;
        {
            const float a0 = (x0 * invQ0) * 1.0f;
            prev0 = 1.0f - a0;
            const float a1 = (x1 * invQ0) * 1.0f;
            prev1 = 1.0f - a1;
        }
        float y30_0 = 0.0f, y30_1 = 0.0f;
        float invQprev = invQ0;                      // invQ[s-1] carry
        float p = 1.0f;
        #pragma unroll
        for (int s = 1; s < NPART; ++s) {
            const float d = Er[s] * invQprev;
            const float m = d * p;
            p = 1.0f - m;
            const float psA = readlane_f(p, s);
            const float psB = readlane_f(p, 32 + s);
            const float psv = hbit ? psB : psA;
            const float invQs = (float)(s + 1) * rcp_nr(c1v * psv);
            // aux step s (inline g = x*invQ[s]; same rounding as R11)
            const float a0 = (x0 * invQs) * prev0;
            prev0 = 1.0f - a0;
            const float a1 = (x1 * invQs) * prev1;
            prev1 = 1.0f - a1;
            if (s == NPART - 2) { y30_0 = prev0; y30_1 = prev1; }
            invQprev = invQs;
        }
        const float invQ31 = invQprev;               // invQ[NPART-1]
        const float Qp1_0 = prev0,          Qp1_1 = prev1;
        const float Qp0_0 = y30_0 * invQ31;
        const float Qp0_1 = y30_1 * invQ31;

        // ---- update + normalize (identical to R11) ----
        const float q0 = (ratio0 * Qp1_0) * rcp_nr(Qp0_0);
        const float q1 = (ratio1 * Qp1_1) * rcp_nr(Qp0_1);
        const float en0 = (-ln_acc(q0)) * inv_beta;
        const float en1 = (-ln_acc(q1)) * inv_beta;

        const float W = red_np(nn0 * en0, nn1 * en1, l32, hbit);
        const float corr = W * inv_snn;
        eps0 = en0 - corr;
        eps1 = en1 - corr;
    }

    out[sysbase + l32]      = eps0;
    out[sysbase + 32 + l32] = eps1;
}

extern "C" void kernel_launch(void* const* d_in, const int* in_sizes, int n_in,
                              void* d_out, int out_size, void* d_ws, size_t ws_size,
                              hipStream_t stream) {
    const float* n_ptr    = (const float*)d_in[0];
    const float* beta_ptr = (const float*)d_in[1];
    const int*   it_ptr   = (const int*)d_in[2];
    float*       out      = (float*)d_out;

    const int B = in_sizes[0] / PORB;   // 2048 systems
    sinkhorn_kernel<<<B / 2, PORB, 0, stream>>>(n_ptr, beta_ptr, it_ptr, out);
}